// Round 8
// baseline (283.860 us; speedup 1.0000x reference)
//
#include <hip/hip_runtime.h>

#define N_B   262144
#define BM    128      // rows/block; 2048 blocks
#define KAUG  288      // 256 (h) + 32 (x-augmentation, only 3 used; cols 259+ zero)
#define LDA   264      // hA row stride in halves (528 B)

typedef _Float16 f16x8 __attribute__((ext_vector_type(8)));
typedef _Float16 f16x4 __attribute__((ext_vector_type(4)));
typedef float    f32x4 __attribute__((ext_vector_type(4)));
typedef float    f32x16 __attribute__((ext_vector_type(16)));

// ---------------------------------------------------------------------------
// Precompute (68 blocks):
//   blocks 0..63 : (l = b>>4, row-group ng = b&15) -> Mt[l][16ng..16ng+16)[*]
//   blocks 64..67: W1t[n][k] = W1[k][n] transpose.
// ---------------------------------------------------------------------------
__global__ void fno_precompute(const float* __restrict__ W1,
                               const float* __restrict__ fw,
                               const float* __restrict__ lw,
                               _Float16* __restrict__ Mt,    // [4][256][KAUG]
                               _Float16* __restrict__ W1t)   // [256][64]
{
    const int t = threadIdx.x;          // 0..255
    const int b = blockIdx.x;
    if (b < 64) {
        const int l  = b >> 4;
        const int ng = b & 15;
        __shared__ float cosTab[256];
        __shared__ float cs[256];
        cosTab[t] = cosf((float)t * (6.28318530717958647692f / 256.0f));
        __syncthreads();
        // cs[t] = irfft(fw_l)[t]
        {
            const float* fwl = fw + l * 129;
            float s = fwl[0];
            #pragma unroll 4
            for (int k = 1; k < 128; ++k)
                s += 2.0f * fwl[k] * cosTab[(k * t) & 255];
            s += fwl[128] * ((t & 1) ? -1.0f : 1.0f);
            cs[t] = s * (1.0f / 256.0f);
        }
        __syncthreads();
        for (int idx = t; idx < 16 * KAUG; idx += 256) {
            const int n = ng * 16 + idx / KAUG;
            const int k = idx % KAUG;
            float v = 0.0f;
            if (k < 253)               v = cs[(n - k - 3) & 255];  // conv: h[k] -> d[k+3]
            if (k == n)                v += lw[l * 256 + n];       // diagonal residual lw
            if (k >= 256 && k < 259)   v = cs[(n - (k - 256)) & 255]; // x rows
            Mt[((size_t)l * 256 + n) * KAUG + k] = (_Float16)v;
        }
    } else {
        const int base = (b - 64) * 4096;
        #pragma unroll
        for (int i = 0; i < 16; ++i) {
            const int idx = base + t + i * 256;
            const int n = idx >> 6, k = idx & 63;
            W1t[idx] = (_Float16)W1[k * 256 + n];
        }
    }
}

// ---------------------------------------------------------------------------
// Fused main kernel. Block = 128 rows x 512 threads (8 waves); wave
// w = (wf = w&3, wr = w>>2) owns the 64-feat x 64-row quadrant
// [64wf..64wf+64) x [64wr..64wr+64); acc[2][2] f32x16 = 64 regs.
// KEY CHANGE vs the 162us 4-wave baseline: 8 waves/block -> 4 waves/SIMD
// (was 2). Same LDS (70KB, 2 blocks/CU), same per-CU MFMA/LDS totals --
// pure TLP to hide the per-kc mfrag L2 latency that 6 rounds of ILP
// attempts (R3/R5 rotates: spill; R2 BM=64: barrier overhead) couldn't.
// Mt L2 requests double (row-quadrant pairs share feats): ~40% L2 peak, ok.
// 32x32x16 MFMA (R4-verified layout); kc=17 dropped (cols 272..287 zero).
// x in cols 256..258; kc=16 reads halves 256..271 -> q2=1 over-reads next
// row's h[0..7] against zero Mt cols 264..271; zeroed pad row guards row 127.
// __launch_bounds__(512,4): cap 128 regs -- acc is only 64, no spill
// (watchdog: WRITE_SIZE must stay ~1MB).
// ---------------------------------------------------------------------------
__global__ __launch_bounds__(512, 4)
void fno_main(const float* __restrict__ mu,
              const float* __restrict__ x,
              const float* __restrict__ b1,
              const float* __restrict__ W2,
              const float* __restrict__ b2,
              const _Float16* __restrict__ Mt,
              const _Float16* __restrict__ W1t,
              float* __restrict__ out)
{
    __shared__ __align__(16) _Float16 hA[(BM + 1) * LDA];  // h + x cols + pad row
    __shared__ float b1s[256];
    __shared__ float W2s[256];
    __shared__ float red3[3][BM];

    const int t    = threadIdx.x;      // 0..511
    const int w    = t >> 6;           // wave 0..7
    const int wf   = w & 3;            // feature quadrant: feats 64wf..+63
    const int wr   = w >> 2;           // row half: rows 64wr..+63
    const int lane = t & 63;
    const int i32  = lane & 31;
    const int q2   = lane >> 5;
    const int r0   = blockIdx.x * BM;
    const int hoff = (64 * wr + i32) * LDA + 8 * q2;   // hfrag base (halves)

    // ---- stage mu -> hA cols 0..63; x -> cols 256..263; zero pad row ----
    {
        const float4* mu4 = (const float4*)mu + (size_t)r0 * 16;  // 16 float4/row
        #pragma unroll
        for (int j = 0; j < 4; ++j) {
            int f = t + 512 * j;                 // 0..2047 = 128 rows * 16
            int row = f >> 4, c4 = f & 15;
            float4 v = mu4[f];
            f16x4 h;
            h[0] = (_Float16)v.x; h[1] = (_Float16)v.y;
            h[2] = (_Float16)v.z; h[3] = (_Float16)v.w;
            *(f16x4*)&hA[row * LDA + c4 * 4] = h;
        }
        if (t < BM) {
            const float* xp = x + (size_t)(r0 + t) * 3;
            f16x8 hx = {(_Float16)xp[0], (_Float16)xp[1], (_Float16)xp[2],
                        (_Float16)0, (_Float16)0, (_Float16)0,
                        (_Float16)0, (_Float16)0};
            *(f16x8*)&hA[t * LDA + 256] = hx;
        }
        if (t < 33) {              // zero the whole pad row (row-127 over-read)
            f16x8 z8 = {};
            *(f16x8*)&hA[BM * LDA + 8 * t] = z8;
        }
        if (t < 256) { b1s[t] = b1[t]; W2s[t] = W2[t]; }
    }
    __syncthreads();

    const f32x16 fz = {0.f,0.f,0.f,0.f, 0.f,0.f,0.f,0.f,
                       0.f,0.f,0.f,0.f, 0.f,0.f,0.f,0.f};
    f32x16 acc[2][2];   // [feat-tile(32)][row-tile(32)], 64 regs

    // ================= encoder: h = relu(mu @ W1 + b1), K = 64 =================
    #pragma unroll
    for (int ft = 0; ft < 2; ++ft)
        #pragma unroll
        for (int rt = 0; rt < 2; ++rt) acc[ft][rt] = fz;

    {
        const _Float16* W1p = W1t + (64 * wf + i32) * 64 + 8 * q2;
        #pragma unroll
        for (int kc = 0; kc < 4; ++kc) {
            f16x8 m0 = *(const f16x8*)(W1p + 16 * kc);
            f16x8 m1 = *(const f16x8*)(W1p + 32 * 64 + 16 * kc);
            #pragma unroll
            for (int rt = 0; rt < 2; ++rt) {
                f16x8 hfrag = *(const f16x8*)&hA[hoff + 32 * rt * LDA + 16 * kc];
                acc[0][rt] = __builtin_amdgcn_mfma_f32_32x32x16_f16(m0, hfrag, acc[0][rt], 0, 0, 0);
                acc[1][rt] = __builtin_amdgcn_mfma_f32_32x32x16_f16(m1, hfrag, acc[1][rt], 0, 0, 0);
            }
        }
    }
    __syncthreads();   // all reads of mu-region done before overwrite
    #pragma unroll
    for (int ft = 0; ft < 2; ++ft)
        #pragma unroll
        for (int rt = 0; rt < 2; ++rt) {
            const int row = 64 * wr + 32 * rt + i32;
            #pragma unroll
            for (int rg = 0; rg < 4; ++rg) {
                const int fb = 64 * wf + 32 * ft + 4 * q2 + 8 * rg;
                const float4 bias = *(const float4*)&b1s[fb];
                f16x4 hv;
                hv[0] = (_Float16)fmaxf(acc[ft][rt][4 * rg + 0] + bias.x, 0.f);
                hv[1] = (_Float16)fmaxf(acc[ft][rt][4 * rg + 1] + bias.y, 0.f);
                hv[2] = (_Float16)fmaxf(acc[ft][rt][4 * rg + 2] + bias.z, 0.f);
                hv[3] = (_Float16)fmaxf(acc[ft][rt][4 * rg + 3] + bias.w, 0.f);
                *(f16x4*)&hA[row * LDA + fb] = hv;
            }
        }

    // ================= 4 Fourier layers: h = relu([h|x] @ M_l) ================
    #pragma unroll 1
    for (int l = 0; l < 4; ++l) {
        __syncthreads();   // hA writes from previous stage visible
        #pragma unroll
        for (int ft = 0; ft < 2; ++ft)
            #pragma unroll
            for (int rt = 0; rt < 2; ++rt) acc[ft][rt] = fz;

        const _Float16* Mlp = Mt + ((size_t)l * 256 + 64 * wf + i32) * KAUG + 8 * q2;
        #pragma unroll
        for (int kc = 0; kc < 17; ++kc) {   // kc=17 (halves 272..287) all-zero: dropped
            f16x8 m0 = *(const f16x8*)(Mlp + 16 * kc);
            f16x8 m1 = *(const f16x8*)(Mlp + 32 * KAUG + 16 * kc);
            #pragma unroll
            for (int rt = 0; rt < 2; ++rt) {
                // kc=16: x cols + zeros + next-row over-read (zero weights)
                f16x8 hfrag = *(const f16x8*)&hA[hoff + 32 * rt * LDA + 16 * kc];
                acc[0][rt] = __builtin_amdgcn_mfma_f32_32x32x16_f16(m0, hfrag, acc[0][rt], 0, 0, 0);
                acc[1][rt] = __builtin_amdgcn_mfma_f32_32x32x16_f16(m1, hfrag, acc[1][rt], 0, 0, 0);
            }
        }

        __syncthreads();   // all hA reads done before overwrite
        #pragma unroll
        for (int ft = 0; ft < 2; ++ft)
            #pragma unroll
            for (int rt = 0; rt < 2; ++rt) {
                const int row = 64 * wr + 32 * rt + i32;
                #pragma unroll
                for (int rg = 0; rg < 4; ++rg) {
                    const int fb = 64 * wf + 32 * ft + 4 * q2 + 8 * rg;
                    f16x4 hv;
                    hv[0] = (_Float16)fmaxf(acc[ft][rt][4 * rg + 0], 0.f);
                    hv[1] = (_Float16)fmaxf(acc[ft][rt][4 * rg + 1], 0.f);
                    hv[2] = (_Float16)fmaxf(acc[ft][rt][4 * rg + 2], 0.f);
                    hv[3] = (_Float16)fmaxf(acc[ft][rt][4 * rg + 3], 0.f);
                    *(f16x4*)&hA[row * LDA + fb] = hv;
                }
            }
    }

    // ================= decoder: out = h @ W2 + b2 =============================
    __syncthreads();
    {
        const int r   = t & 127;       // row
        const int seg = t >> 7;        // 4 threads/row, 64 cols each
        const int n0  = seg * 64;
        float s = 0.f;
        #pragma unroll
        for (int j = 0; j < 8; ++j) {
            f16x8 v = *(const f16x8*)&hA[r * LDA + n0 + 8 * j];
            const float* wp = &W2s[n0 + 8 * j];
            s += (float)v[0] * wp[0] + (float)v[1] * wp[1]
               + (float)v[2] * wp[2] + (float)v[3] * wp[3]
               + (float)v[4] * wp[4] + (float)v[5] * wp[5]
               + (float)v[6] * wp[6] + (float)v[7] * wp[7];
        }
        if (seg) red3[seg - 1][r] = s;
        __syncthreads();
        if (!seg)
            out[r0 + r] = s + red3[0][r] + red3[1][r] + red3[2][r] + b2[0];
    }
}

// ---------------------------------------------------------------------------
extern "C" void kernel_launch(void* const* d_in, const int* in_sizes, int n_in,
                              void* d_out, int out_size, void* d_ws, size_t ws_size,
                              hipStream_t stream) {
    const float* mu = (const float*)d_in[0];
    const float* x  = (const float*)d_in[1];
    const float* W1 = (const float*)d_in[2];
    const float* b1 = (const float*)d_in[3];
    const float* fw = (const float*)d_in[4];
    const float* lw = (const float*)d_in[5];
    const float* W2 = (const float*)d_in[6];
    const float* b2 = (const float*)d_in[7];
    float* out = (float*)d_out;

    _Float16* Mt  = (_Float16*)d_ws;
    _Float16* W1t = Mt + 4 * 256 * KAUG;

    fno_precompute<<<68, 256, 0, stream>>>(W1, fw, lw, Mt, W1t);
    fno_main<<<N_B / BM, 512, 0, stream>>>(mu, x, b1, W2, b2, Mt, W1t, out);
}

// Round 9
// 235.958 us; speedup vs baseline: 1.2030x; 1.2030x over previous
//
#include <hip/hip_runtime.h>

#define N_B   262144
#define BM    128
#define LDA   264   // halves/row; cols 0..252 = h[0..252], 253..255 = x (d-shifted
                    // layout: col k holds d[(k+3)%256] -> UNIFORM circulant weight
                    // cs[(n-k-3)&255]); cols 260..263 = stash {h252..h255}

typedef _Float16 f16x8 __attribute__((ext_vector_type(8)));
typedef _Float16 f16x4 __attribute__((ext_vector_type(4)));
typedef float    f32x4 __attribute__((ext_vector_type(4)));

// ---------------------------------------------------------------------------
// Precompute (8 blocks x 256):
//   blocks 0..3: cs_l = irfft(fw_l); csr8G[l][p][i] = cs[(256-(i+p))&255]
//                (8 pre-shifted copies so A-frags are aligned b128 in LDS).
//   blocks 4..7: W1t[n][k] = W1[k][n].
// Mt is GONE -- the 256x256 circulant is generated from 4 KB of cs tables.
// ---------------------------------------------------------------------------
__global__ void fno_precompute(const float* __restrict__ W1,
                               const float* __restrict__ fw,
                               _Float16* __restrict__ csr8G,  // [4][8][256]
                               _Float16* __restrict__ W1t)    // [256][64]
{
    const int t = threadIdx.x;
    const int b = blockIdx.x;
    if (b < 4) {
        const int l = b;
        __shared__ float cosTab[256];
        __shared__ float cs[256];
        cosTab[t] = cosf((float)t * (6.28318530717958647692f / 256.0f));
        __syncthreads();
        const float* fwl = fw + l * 129;
        float s = fwl[0];
        #pragma unroll 4
        for (int k = 1; k < 128; ++k)
            s += 2.0f * fwl[k] * cosTab[(k * t) & 255];
        s += fwl[128] * ((t & 1) ? -1.0f : 1.0f);
        cs[t] = s * (1.0f / 256.0f);
        __syncthreads();
        #pragma unroll
        for (int p = 0; p < 8; ++p)
            csr8G[(l * 8 + p) * 256 + t] = (_Float16)cs[(256 - (t + p)) & 255];
    } else {
        const int base = (b - 4) * 4096;
        #pragma unroll
        for (int i = 0; i < 16; ++i) {
            const int idx = base + t + i * 256;
            const int n = idx >> 6, k = idx & 63;
            W1t[idx] = (_Float16)W1[k * 256 + n];
        }
    }
}

// ---------------------------------------------------------------------------
// Fused main kernel -- R0's 162us skeleton (BM=128, 4 waves, 16x16x32) with
// the Mt L2 stream replaced by on-the-fly circulant A-frags from LDS:
//   frag(ft,ks) element e = cs[(n - k0 - e - 3)&255] = csr8 copy (j0&7) at
//   aligned index (j0&~7), j0 = (3 + k0 - n)&255, k0 = 32ks+8q, n = 64w+16ft+i16.
// The lw diagonal (previously folded into Mt) is an f32 epilogue fixup:
// read h_prev from the store address, acc += lw*h_prev, relu, store.
// Zero global loads between barriers (no vmcnt drains); MFMA 9ks->8ks.
// csr8 for layer l+1 is restaged during layer l's epilogue phase (between
// the two barriers: K-loop reads of csr8(l) are done, next reads after the
// following barrier). Stash (cols 260..263) holds h[252..255] for the
// z-fixup and decoder; x at cols 253..255 is never overwritten (the only
// feat-quad touching those cols, fb=252, is special-cased to col252+stash).
// ---------------------------------------------------------------------------
__global__ __launch_bounds__(256, 2)
void fno_main(const float* __restrict__ mu,
              const float* __restrict__ x,
              const float* __restrict__ b1,
              const float* __restrict__ lw,
              const float* __restrict__ W2,
              const float* __restrict__ b2,
              const _Float16* __restrict__ csr8G,
              const _Float16* __restrict__ W1t,
              float* __restrict__ out)
{
    __shared__ __align__(16) _Float16 hA[BM * LDA];     // 67,584 B
    __shared__ __align__(16) _Float16 csr8[8 * 264];    //  4,224 B (264-stride de-banks copies)
    __shared__ float lws[4 * 256];
    __shared__ float b1s[256];
    __shared__ float W2s[260];   // [253..255]=0 (x cols), [256..259]=W2[252..255]
    __shared__ float red[BM];

    const int t    = threadIdx.x;
    const int w    = t >> 6;
    const int lane = t & 63;
    const int i16  = lane & 15;
    const int q    = lane >> 4;
    const int r0   = blockIdx.x * BM;
    const int hoff = i16 * LDA + 8 * q;
    const int p8   = t >> 5;            // csr8 staging: copy index
    const int i08  = (t & 31) * 8;      //               element base

    // ---- stage: mu -> cols 0..63; x -> cols 253..255; csr8(l=0); lw/b1/W2 ----
    {
        const float4* mu4 = (const float4*)mu + (size_t)r0 * 16;
        #pragma unroll
        for (int j = 0; j < 8; ++j) {
            int f = t + 256 * j;
            int row = f >> 4, c4 = f & 15;
            float4 v = mu4[f];
            f16x4 h;
            h[0] = (_Float16)v.x; h[1] = (_Float16)v.y;
            h[2] = (_Float16)v.z; h[3] = (_Float16)v.w;
            *(f16x4*)&hA[row * LDA + c4 * 4] = h;
        }
        if (t < BM) {
            const float* xp = x + (size_t)(r0 + t) * 3;
            hA[t * LDA + 253] = (_Float16)xp[0];
            hA[t * LDA + 254] = (_Float16)xp[1];
            hA[t * LDA + 255] = (_Float16)xp[2];
        }
        *(f16x8*)&csr8[p8 * 264 + i08] = *(const f16x8*)&csr8G[p8 * 256 + i08];
        lws[t]       = lw[t];
        lws[256 + t] = lw[256 + t];
        lws[512 + t] = lw[512 + t];
        lws[768 + t] = lw[768 + t];
        b1s[t] = b1[t];
        W2s[t] = (t < 253) ? W2[t] : 0.0f;
        if (t < 4) W2s[256 + t] = W2[252 + t];
    }
    __syncthreads();

    const f32x4 fz = {0.f, 0.f, 0.f, 0.f};
    f32x4 acc[4][8];

    // ================= encoder: h = relu(mu @ W1 + b1), K = 64 =================
    #pragma unroll
    for (int ft = 0; ft < 4; ++ft)
        #pragma unroll
        for (int rt = 0; rt < 8; ++rt) acc[ft][rt] = fz;

    #pragma unroll
    for (int ks = 0; ks < 2; ++ks) {
        const int kb = 32 * ks;
        f16x8 mfrag[4];
        #pragma unroll
        for (int ft = 0; ft < 4; ++ft) {
            int n = 64 * w + 16 * ft + i16;
            mfrag[ft] = *(const f16x8*)(W1t + n * 64 + kb + 8 * q);
        }
        #pragma unroll
        for (int rt = 0; rt < 8; ++rt) {
            f16x8 hfrag = *(const f16x8*)&hA[hoff + 16 * rt * LDA + kb];
            #pragma unroll
            for (int ft = 0; ft < 4; ++ft)
                acc[ft][rt] = __builtin_amdgcn_mfma_f32_16x16x32_f16(
                    mfrag[ft], hfrag, acc[ft][rt], 0, 0, 0);
        }
    }
    __syncthreads();
    #pragma unroll
    for (int ft = 0; ft < 4; ++ft) {
        const int f = 64 * w + 16 * ft + 4 * q;
        const float4 bias = *(const float4*)&b1s[f];
        #pragma unroll
        for (int rt = 0; rt < 8; ++rt) {
            const int row = 16 * rt + i16;
            f32x4 v = acc[ft][rt];
            f16x4 hv;
            hv[0] = (_Float16)fmaxf(v[0] + bias.x, 0.f);
            hv[1] = (_Float16)fmaxf(v[1] + bias.y, 0.f);
            hv[2] = (_Float16)fmaxf(v[2] + bias.z, 0.f);
            hv[3] = (_Float16)fmaxf(v[3] + bias.w, 0.f);
            if (f == 252) {   // don't clobber x at 253..255: col252 + stash
                hA[row * LDA + 252] = hv[0];
                *(f16x4*)&hA[row * LDA + 260] = hv;
            } else {
                *(f16x4*)&hA[row * LDA + f] = hv;
            }
        }
    }

    // ================= 4 Fourier layers: h = relu(circulant(d) + lw*h) ========
    const int bl = (3 + 8 * q - 64 * w - i16) & 255;   // lane csr base

    #pragma unroll 1
    for (int l = 0; l < 4; ++l) {
        __syncthreads();   // h_prev + csr8(l) visible
        #pragma unroll
        for (int ft = 0; ft < 4; ++ft)
            #pragma unroll
            for (int rt = 0; rt < 8; ++rt) acc[ft][rt] = fz;

        #pragma unroll
        for (int ks = 0; ks < 8; ++ks) {
            const int kb = 32 * ks;
            f16x8 mf[4];
            #pragma unroll
            for (int ft = 0; ft < 4; ++ft) {
                const int j0 = (bl + kb + 256 - 16 * ft) & 255;
                mf[ft] = *(const f16x8*)&csr8[(j0 & 7) * 264 + (j0 & 248)];
            }
            #pragma unroll
            for (int rt = 0; rt < 8; ++rt) {
                f16x8 hfrag = *(const f16x8*)&hA[hoff + 16 * rt * LDA + kb];
                #pragma unroll
                for (int ft = 0; ft < 4; ++ft)
                    acc[ft][rt] = __builtin_amdgcn_mfma_f32_16x16x32_f16(
                        mf[ft], hfrag, acc[ft][rt], 0, 0, 0);
            }
        }
        __syncthreads();   // all csr8(l)/hA reads done

        if (l < 3)         // restage csr8(l+1) during the epilogue phase
            *(f16x8*)&csr8[p8 * 264 + i08] =
                *(const f16x8*)&csr8G[((l + 1) * 8 + p8) * 256 + i08];

        const float* lwl = lws + l * 256;
        #pragma unroll
        for (int ft = 0; ft < 4; ++ft) {
            const int f = 64 * w + 16 * ft + 4 * q;
            const float4 lw4 = *(const float4*)&lwl[f];
            #pragma unroll
            for (int rt = 0; rt < 8; ++rt) {
                const int row = 16 * rt + i16;
                // z-fixup: h_prev lives at exactly the store address
                const int za = row * LDA + ((f == 252) ? 260 : f);
                f16x4 hp = *(const f16x4*)&hA[za];
                f32x4 v = acc[ft][rt];
                f16x4 hv;
                hv[0] = (_Float16)fmaxf(v[0] + lw4.x * (float)hp[0], 0.f);
                hv[1] = (_Float16)fmaxf(v[1] + lw4.y * (float)hp[1], 0.f);
                hv[2] = (_Float16)fmaxf(v[2] + lw4.z * (float)hp[2], 0.f);
                hv[3] = (_Float16)fmaxf(v[3] + lw4.w * (float)hp[3], 0.f);
                if (f == 252) {
                    hA[row * LDA + 252] = hv[0];
                    *(f16x4*)&hA[row * LDA + 260] = hv;
                } else {
                    *(f16x4*)&hA[row * LDA + f] = hv;
                }
            }
        }
    }

    // ================= decoder: out = h @ W2 + b2 =============================
    __syncthreads();
    {
        const int r  = t & 127;
        const int hf = t >> 7;
        const int n0 = hf * 128;
        float s = 0.f;
        #pragma unroll
        for (int j = 0; j < 16; ++j) {
            f16x8 v = *(const f16x8*)&hA[r * LDA + n0 + 8 * j];
            const float* wp = &W2s[n0 + 8 * j];
            s += (float)v[0] * wp[0] + (float)v[1] * wp[1]
               + (float)v[2] * wp[2] + (float)v[3] * wp[3]
               + (float)v[4] * wp[4] + (float)v[5] * wp[5]
               + (float)v[6] * wp[6] + (float)v[7] * wp[7];
        }
        if (hf) {   // h[253..255] from stash (cols 253..255 were x, W2s=0 there)
            f16x4 st = *(const f16x4*)&hA[r * LDA + 260];
            s += (float)st[1] * W2s[257] + (float)st[2] * W2s[258]
               + (float)st[3] * W2s[259];
            red[r] = s;
        }
        __syncthreads();
        if (!hf) out[r0 + r] = s + red[r] + b2[0];
    }
}

// ---------------------------------------------------------------------------
extern "C" void kernel_launch(void* const* d_in, const int* in_sizes, int n_in,
                              void* d_out, int out_size, void* d_ws, size_t ws_size,
                              hipStream_t stream) {
    const float* mu = (const float*)d_in[0];
    const float* x  = (const float*)d_in[1];
    const float* W1 = (const float*)d_in[2];
    const float* b1 = (const float*)d_in[3];
    const float* fw = (const float*)d_in[4];
    const float* lw = (const float*)d_in[5];
    const float* W2 = (const float*)d_in[6];
    const float* b2 = (const float*)d_in[7];
    float* out = (float*)d_out;

    _Float16* csr8G = (_Float16*)d_ws;            // 4*8*256 halves = 16 KB
    _Float16* W1t   = csr8G + 4 * 8 * 256;        // 32 KB

    fno_precompute<<<8, 256, 0, stream>>>(W1, fw, csr8G, W1t);
    fno_main<<<N_B / BM, 256, 0, stream>>>(mu, x, b1, lw, W2, b2, csr8G, W1t, out);
}

// Round 10
// 224.939 us; speedup vs baseline: 1.2619x; 1.0490x over previous
//
#include <hip/hip_runtime.h>

#define N_B   262144
#define BM    128
#define LDA   264   // halves/row; cols 0..252 = h[0..252], 253..255 = x (d-shifted
                    // layout: col k holds d[(k+3)%256] -> uniform circulant weight
                    // cs[(n-k-3)&255]); cols 260..263 = stash {h252..h255}
#define CSTR  520   // csr copy stride in halves (de-banks the 8 copies by 4 banks)

typedef _Float16 f16x8 __attribute__((ext_vector_type(8)));
typedef _Float16 f16x4 __attribute__((ext_vector_type(4)));
typedef float    f32x4 __attribute__((ext_vector_type(4)));
typedef float    f32x16 __attribute__((ext_vector_type(16)));

// ---------------------------------------------------------------------------
// Precompute (8 blocks x 256):
//   blocks 0..3: cs_l = irfft(fw_l); csrG[l][p][i] = cs[(-(i+p))&255], i<512
//                (8 pre-shifted DOUBLED copies: wrap-free indexing in fno_main,
//                 so each mf address is base + compile-time 16*kc immediate).
//   blocks 4..7: W1t[n][k] = W1[k][n].
// ---------------------------------------------------------------------------
__global__ void fno_precompute(const float* __restrict__ W1,
                               const float* __restrict__ fw,
                               _Float16* __restrict__ csrG,  // [4][8][512]
                               _Float16* __restrict__ W1t)   // [256][64]
{
    const int t = threadIdx.x;
    const int b = blockIdx.x;
    if (b < 4) {
        const int l = b;
        __shared__ float cosTab[256];
        __shared__ float cs[256];
        cosTab[t] = cosf((float)t * (6.28318530717958647692f / 256.0f));
        __syncthreads();
        const float* fwl = fw + l * 129;
        float s = fwl[0];
        #pragma unroll 4
        for (int k = 1; k < 128; ++k)
            s += 2.0f * fwl[k] * cosTab[(k * t) & 255];
        s += fwl[128] * ((t & 1) ? -1.0f : 1.0f);
        cs[t] = s * (1.0f / 256.0f);
        __syncthreads();
        #pragma unroll
        for (int j = 0; j < 16; ++j) {
            const int idx = t + 256 * j;          // = p*512 + i
            const int p = idx >> 9, i = idx & 511;
            csrG[l * 4096 + idx] = (_Float16)cs[(1024 - i - p) & 255];
        }
    } else {
        const int base = (b - 4) * 4096;
        #pragma unroll
        for (int i = 0; i < 16; ++i) {
            const int idx = base + t + i * 256;
            const int n = idx >> 6, k = idx & 63;
            W1t[idx] = (_Float16)W1[k * 256 + n];
        }
    }
}

// ---------------------------------------------------------------------------
// Fused main kernel. BM=128 x 256 threads (4 waves), 32x32x16 MFMA,
// acc[2][4] f32x16 = 128 regs; 2 blocks/CU (LDS 78.4 KB).
// vs R8 (160us, spilled 19MB): same circulant-from-LDS weights, but
//  (1) 512-entry csr copies -> wrap-free mf addressing: copy (blf&7) is
//      kc-invariant, so each ft needs ONE base reg + imm 16*kc (R8 kept ~32
//      wrapped addresses live -> 256-reg cap -> 36B/thread scratch).
//  (2) 32x32x16 (R4-verified D layout): -17% MFMA cycles, mf regs 16->8,
//      K=256 = exactly 16 chunks (no over-read, no pad row).
//  (3) lw read from L2 in epilogue (lane-uniform float4 per quarter-group)
//      to fund the 8.3KB csr table in LDS.
// z-fixup: h_prev is read from the exact slot the same thread overwrites
// (ownership is layer-invariant), x cols 253..255 never clobbered (the
// fb==252 group diverts to col252 + stash 260..263).
// ---------------------------------------------------------------------------
__global__ __launch_bounds__(256, 2)
void fno_main(const float* __restrict__ mu,
              const float* __restrict__ x,
              const float* __restrict__ b1,
              const float* __restrict__ lw,
              const float* __restrict__ W2,
              const float* __restrict__ b2,
              const _Float16* __restrict__ csrG,
              const _Float16* __restrict__ W1t,
              float* __restrict__ out)
{
    __shared__ __align__(16) _Float16 hA[BM * LDA];      // 67,584 B
    __shared__ __align__(16) _Float16 csr[8 * CSTR];     //  8,320 B
    __shared__ float b1s[256];
    __shared__ float W2s[260];   // [253..255]=0 (x cols), [256..259]=W2[252..255]
    __shared__ float red[BM];

    const int t    = threadIdx.x;
    const int w    = t >> 6;
    const int lane = t & 63;
    const int i32  = lane & 31;
    const int q2   = lane >> 5;
    const int r0   = blockIdx.x * BM;
    const int hoff = i32 * LDA + 8 * q2;

    // csr A-frag bases: blf = (3 + 8q2 - n)&255 with n = 64w + 32ft + i32;
    // copy = blf&7 (kc-invariant), element base = blf&248; +16*kc per chunk.
    const int blf0 = (3 + 8 * q2 - 64 * w - i32) & 255;
    const int blf1 = (blf0 - 32) & 255;
    const int a0   = (blf0 & 7) * CSTR + (blf0 & 248);
    const int a1   = (blf1 & 7) * CSTR + (blf1 & 248);

    // ---- stage: mu -> cols 0..63; x -> cols 253..255; csr(l=0); b1/W2 ----
    {
        const float4* mu4 = (const float4*)mu + (size_t)r0 * 16;
        #pragma unroll
        for (int j = 0; j < 8; ++j) {
            int f = t + 256 * j;
            int row = f >> 4, c4 = f & 15;
            float4 v = mu4[f];
            f16x4 h;
            h[0] = (_Float16)v.x; h[1] = (_Float16)v.y;
            h[2] = (_Float16)v.z; h[3] = (_Float16)v.w;
            *(f16x4*)&hA[row * LDA + c4 * 4] = h;
        }
        if (t < BM) {
            const float* xp = x + (size_t)(r0 + t) * 3;
            hA[t * LDA + 253] = (_Float16)xp[0];
            hA[t * LDA + 254] = (_Float16)xp[1];
            hA[t * LDA + 255] = (_Float16)xp[2];
        }
        #pragma unroll
        for (int rep = 0; rep < 2; ++rep) {     // stage 8x512 halves, strided CSTR
            const int g = t + 256 * rep;
            const int p = g >> 6, i = (g & 63) * 8;
            *(f16x8*)&csr[p * CSTR + i] = *(const f16x8*)&csrG[p * 512 + i];
        }
        b1s[t] = b1[t];
        W2s[t] = (t < 253) ? W2[t] : 0.0f;
        if (t < 4) W2s[256 + t] = W2[252 + t];
    }
    __syncthreads();

    const f32x16 fz = {0.f,0.f,0.f,0.f, 0.f,0.f,0.f,0.f,
                       0.f,0.f,0.f,0.f, 0.f,0.f,0.f,0.f};
    f32x16 acc[2][4];   // [feat-tile(32)][row-tile(32)], 128 regs

    // ================= encoder: h = relu(mu @ W1 + b1), K = 64 =================
    #pragma unroll
    for (int ft = 0; ft < 2; ++ft)
        #pragma unroll
        for (int rt = 0; rt < 4; ++rt) acc[ft][rt] = fz;

    {
        const _Float16* W1p = W1t + (64 * w + i32) * 64 + 8 * q2;
        #pragma unroll
        for (int kc = 0; kc < 4; ++kc) {
            f16x8 m0 = *(const f16x8*)(W1p + 16 * kc);
            f16x8 m1 = *(const f16x8*)(W1p + 32 * 64 + 16 * kc);
            #pragma unroll
            for (int rt = 0; rt < 4; ++rt) {
                f16x8 hfrag = *(const f16x8*)&hA[hoff + 32 * rt * LDA + 16 * kc];
                acc[0][rt] = __builtin_amdgcn_mfma_f32_32x32x16_f16(m0, hfrag, acc[0][rt], 0, 0, 0);
                acc[1][rt] = __builtin_amdgcn_mfma_f32_32x32x16_f16(m1, hfrag, acc[1][rt], 0, 0, 0);
            }
        }
    }
    __syncthreads();   // all reads of mu-region done before overwrite
    #pragma unroll
    for (int ft = 0; ft < 2; ++ft)
        #pragma unroll
        for (int rt = 0; rt < 4; ++rt) {
            const int row = 32 * rt + i32;
            #pragma unroll
            for (int rg = 0; rg < 4; ++rg) {
                const int fb = 64 * w + 32 * ft + 4 * q2 + 8 * rg;
                const float4 bias = *(const float4*)&b1s[fb];
                f16x4 hv;
                hv[0] = (_Float16)fmaxf(acc[ft][rt][4 * rg + 0] + bias.x, 0.f);
                hv[1] = (_Float16)fmaxf(acc[ft][rt][4 * rg + 1] + bias.y, 0.f);
                hv[2] = (_Float16)fmaxf(acc[ft][rt][4 * rg + 2] + bias.z, 0.f);
                hv[3] = (_Float16)fmaxf(acc[ft][rt][4 * rg + 3] + bias.w, 0.f);
                if (fb == 252) {   // keep x at 253..255: col252 + stash
                    hA[row * LDA + 252] = hv[0];
                    *(f16x4*)&hA[row * LDA + 260] = hv;
                } else {
                    *(f16x4*)&hA[row * LDA + fb] = hv;
                }
            }
        }

    // ================= 4 Fourier layers: h = relu(circ(d) + lw*h) =============
    #pragma unroll 1
    for (int l = 0; l < 4; ++l) {
        __syncthreads();   // h_prev + csr(l) visible
        #pragma unroll
        for (int ft = 0; ft < 2; ++ft)
            #pragma unroll
            for (int rt = 0; rt < 4; ++rt) acc[ft][rt] = fz;

        #pragma unroll
        for (int kc = 0; kc < 16; ++kc) {
            f16x8 m0 = *(const f16x8*)&csr[a0 + 16 * kc];
            f16x8 m1 = *(const f16x8*)&csr[a1 + 16 * kc];
            #pragma unroll
            for (int rt = 0; rt < 4; ++rt) {
                f16x8 hfrag = *(const f16x8*)&hA[hoff + 32 * rt * LDA + 16 * kc];
                acc[0][rt] = __builtin_amdgcn_mfma_f32_32x32x16_f16(m0, hfrag, acc[0][rt], 0, 0, 0);
                acc[1][rt] = __builtin_amdgcn_mfma_f32_32x32x16_f16(m1, hfrag, acc[1][rt], 0, 0, 0);
            }
        }
        __syncthreads();   // all csr(l)/hA reads done

        if (l < 3) {       // restage csr(l+1) during the epilogue phase
            #pragma unroll
            for (int rep = 0; rep < 2; ++rep) {
                const int g = t + 256 * rep;
                const int p = g >> 6, i = (g & 63) * 8;
                *(f16x8*)&csr[p * CSTR + i] =
                    *(const f16x8*)&csrG[(l + 1) * 4096 + p * 512 + i];
            }
        }

        const float* lwl = lw + l * 256;
        #pragma unroll
        for (int ft = 0; ft < 2; ++ft)
            #pragma unroll
            for (int rt = 0; rt < 4; ++rt) {
                const int row = 32 * rt + i32;
                #pragma unroll
                for (int rg = 0; rg < 4; ++rg) {
                    const int fb = 64 * w + 32 * ft + 4 * q2 + 8 * rg;
                    const int za = row * LDA + ((fb == 252) ? 260 : fb);
                    f16x4 hp = *(const f16x4*)&hA[za];      // h_prev (own slot)
                    float4 lw4 = *(const float4*)(lwl + fb); // L2, lane-group bcast
                    f16x4 hv;
                    hv[0] = (_Float16)fmaxf(acc[ft][rt][4 * rg + 0] + lw4.x * (float)hp[0], 0.f);
                    hv[1] = (_Float16)fmaxf(acc[ft][rt][4 * rg + 1] + lw4.y * (float)hp[1], 0.f);
                    hv[2] = (_Float16)fmaxf(acc[ft][rt][4 * rg + 2] + lw4.z * (float)hp[2], 0.f);
                    hv[3] = (_Float16)fmaxf(acc[ft][rt][4 * rg + 3] + lw4.w * (float)hp[3], 0.f);
                    if (fb == 252) {
                        hA[row * LDA + 252] = hv[0];
                        *(f16x4*)&hA[row * LDA + 260] = hv;
                    } else {
                        *(f16x4*)&hA[row * LDA + fb] = hv;
                    }
                }
            }
    }

    // ================= decoder: out = h @ W2 + b2 =============================
    __syncthreads();
    {
        const int r  = t & 127;
        const int hf = t >> 7;
        const int n0 = hf * 128;
        float s = 0.f;
        #pragma unroll
        for (int j = 0; j < 16; ++j) {
            f16x8 v = *(const f16x8*)&hA[r * LDA + n0 + 8 * j];
            const float* wp = &W2s[n0 + 8 * j];
            s += (float)v[0] * wp[0] + (float)v[1] * wp[1]
               + (float)v[2] * wp[2] + (float)v[3] * wp[3]
               + (float)v[4] * wp[4] + (float)v[5] * wp[5]
               + (float)v[6] * wp[6] + (float)v[7] * wp[7];
        }
        if (hf) {   // h[253..255] from stash (cols 253..255 are x, W2s=0 there)
            f16x4 st = *(const f16x4*)&hA[r * LDA + 260];
            s += (float)st[1] * W2s[257] + (float)st[2] * W2s[258]
               + (float)st[3] * W2s[259];
            red[r] = s;
        }
        __syncthreads();
        if (!hf) out[r0 + r] = s + red[r] + b2[0];
    }
}

// ---------------------------------------------------------------------------
extern "C" void kernel_launch(void* const* d_in, const int* in_sizes, int n_in,
                              void* d_out, int out_size, void* d_ws, size_t ws_size,
                              hipStream_t stream) {
    const float* mu = (const float*)d_in[0];
    const float* x  = (const float*)d_in[1];
    const float* W1 = (const float*)d_in[2];
    const float* b1 = (const float*)d_in[3];
    const float* fw = (const float*)d_in[4];
    const float* lw = (const float*)d_in[5];
    const float* W2 = (const float*)d_in[6];
    const float* b2 = (const float*)d_in[7];
    float* out = (float*)d_out;

    _Float16* csrG = (_Float16*)d_ws;          // 4*8*512 halves = 32 KB
    _Float16* W1t  = csrG + 4 * 8 * 512;       // 32 KB

    fno_precompute<<<8, 256, 0, stream>>>(W1, fw, csrG, W1t);
    fno_main<<<N_B / BM, 256, 0, stream>>>(mu, x, b1, lw, W2, b2, csrG, W1t, out);
}